// Round 2
// baseline (257.037 us; speedup 1.0000x reference)
//
#include <hip/hip_runtime.h>

// Problem constants
#define S_   16384
#define T_   16384
#define B_   32
#define NEDGES (S_ * 64)       // 1,048,576
#define GP_  256               // producer blocks, 4096 edges each
#define EPG  4096              // edges per producer block
#define NBKT 512               // buckets of 32 targets
#define TPB  32                // targets per bucket
#define CAP_SRT 2560           // per-bucket records: lambda=2048, +11 sigma

// weight = clip(att,0,1) * 0.9^delay, delay in [0,6). Exact bit-product.
__device__ __forceinline__ float edge_weight(float a, int d) {
  float w = fminf(fmaxf(a, 0.0f), 1.0f);
  float r = (d & 1) ? 0.9f : 1.0f;
  r = (d & 2) ? r * 0.81f   : r;
  r = (d & 4) ? r * 0.6561f : r;
  return w * r;
}

// ---------------------------------------------------------------------------
// K1: transpose 64 sources of spikes + LDS counting-sort of 4096 edges by
// bucket + ONE contiguous 32 KB flush (full lines, no padding, no spill).
// rec[g][i], i in [0,4096): records {meta = tl<<14 | src, w_bits} grouped by
// bucket; ofse[g][bkt] = end<<16 | start (within-block slice bounds).
__global__ __launch_bounds__(1024) void produce(
    const float* __restrict__ spikes,
    const float* __restrict__ att,
    const int*   __restrict__ tgt,
    const int*   __restrict__ del,
    float*        __restrict__ spikesT,
    int2*         __restrict__ rec,
    unsigned int* __restrict__ ofse) {
  __shared__ float tile[64][33];        // 8.4 KB
  __shared__ int4  sbuf4[EPG / 2];      // 32 KB: 4096 int2 records
  __shared__ int   cnt5[NBKT], cur5[NBKT], sofs5[NBKT];
  __shared__ int   wtot[8];
  int2* buf = (int2*)sbuf4;

  const int g   = blockIdx.x;
  const int tid = threadIdx.x;
  if (tid < NBKT) cnt5[tid] = 0;

  // -- transpose sources [g*64, g*64+64): load half
  const int s0 = g * 64;
  {
    const int x = tid & 63, y = tid >> 6;       // y 0..15
    tile[x][y]      = spikes[(size_t)y        * S_ + s0 + x];
    tile[x][y + 16] = spikes[(size_t)(y + 16) * S_ + s0 + x];
  }

  // -- load my 4 edges (kept in registers across all phases)
  const int e4  = g * 1024 + tid;
  int4   t = reinterpret_cast<const int4*>(tgt)[e4];
  float4 a = reinterpret_cast<const float4*>(att)[e4];
  int4   d = reinterpret_cast<const int4*>(del)[e4];
  const int src = (e4 * 4) >> 6;                // 4 consecutive edges: 1 source

  __syncthreads();                              // cnt5 init + tile visible

  // -- transpose write
  {
    const int b = tid & 31, j = tid >> 5;       // j 0..31
    spikesT[(size_t)(s0 + j)      * 32 + b] = tile[j][b];
    spikesT[(size_t)(s0 + j + 32) * 32 + b] = tile[j + 32][b];
  }

  // -- pass 1: bucket histogram (ds_add, no return needed)
  const int bk0 = t.x >> 5, bk1 = t.y >> 5, bk2 = t.z >> 5, bk3 = t.w >> 5;
  __hip_atomic_fetch_add(&cnt5[bk0], 1, __ATOMIC_RELAXED, __HIP_MEMORY_SCOPE_WORKGROUP);
  __hip_atomic_fetch_add(&cnt5[bk1], 1, __ATOMIC_RELAXED, __HIP_MEMORY_SCOPE_WORKGROUP);
  __hip_atomic_fetch_add(&cnt5[bk2], 1, __ATOMIC_RELAXED, __HIP_MEMORY_SCOPE_WORKGROUP);
  __hip_atomic_fetch_add(&cnt5[bk3], 1, __ATOMIC_RELAXED, __HIP_MEMORY_SCOPE_WORKGROUP);
  __syncthreads();

  // -- exclusive scan of 512 bins: waves 0..7 shuffle-scan 64 each + combine
  int v = 0, incl = 0;
  if (tid < NBKT) {
    v = cnt5[tid];
    incl = v;
#pragma unroll
    for (int off = 1; off < 64; off <<= 1) {
      int u = __shfl_up(incl, off);
      if ((tid & 63) >= off) incl += u;
    }
    if ((tid & 63) == 63) wtot[tid >> 6] = incl;
  }
  __syncthreads();
  if (tid < NBKT) {
    int base = 0;
    const int wv = tid >> 6;
    for (int i = 0; i < wv; ++i) base += wtot[i];
    const int start = base + incl - v;
    sofs5[tid] = start;
    cur5[tid]  = start;
  }
  __syncthreads();

  // -- pass 2: weight + place into LDS at bucket cursor (exact, no overflow)
#define PUT(BK, TL, AV, DV)                                                   \
  {                                                                           \
    int p = __hip_atomic_fetch_add(&cur5[BK], 1, __ATOMIC_RELAXED,            \
                                   __HIP_MEMORY_SCOPE_WORKGROUP);             \
    buf[p] = make_int2(((TL) << 14) | src,                                    \
                       __float_as_int(edge_weight((AV), (DV))));              \
  }
  PUT(bk0, t.x & 31, a.x, d.x)
  PUT(bk1, t.y & 31, a.y, d.y)
  PUT(bk2, t.z & 31, a.z, d.z)
  PUT(bk3, t.w & 31, a.w, d.w)
#undef PUT
  __syncthreads();

  // -- flush: one contiguous 32 KB stream of full lines (int4 x2 per thread)
  int4* recO = reinterpret_cast<int4*>(rec) + (size_t)g * (EPG / 2);
  recO[tid]        = sbuf4[tid];
  recO[tid + 1024] = sbuf4[tid + 1024];
  if (tid < NBKT)
    ofse[(size_t)g * NBKT + tid] =
        ((unsigned)cur5[tid] << 16) | (unsigned)sofs5[tid];   // coalesced
}

// ---------------------------------------------------------------------------
// K2 (v2): bucket k gathers its 256 slices (dense coalesced lines) into LDS,
// then ONE pass: each half-wave broadcasts a record, lane b = batch b, and
// accumulates w*spike directly into otile[tl][b] via ds_add_f32.
// Bank math: addr = tl*33 + b  ->  bank (tl+b)%32: all 32 lanes of a
// half-wave hit distinct banks; the wave's two half-waves give 2-way
// aliasing (free). No fine sort, no 32-bin contended atomics, no srt buffer.
__global__ __launch_bounds__(512) void consume(
    const int2*  __restrict__ rec,
    const unsigned int* __restrict__ ofse,
    const float* __restrict__ spikesT,
    float* __restrict__ out) {
  __shared__ int2  raw[CAP_SRT];        // 20 KB unsorted stage
  __shared__ float otile[TPB][33];      // 4.2 KB accumulator (padded)
  __shared__ unsigned sse[GP_];
  __shared__ int   sstart[GP_];
  __shared__ int   wtot4[4];

  const int k   = blockIdx.x;
  const int tid = threadIdx.x;
  const int b   = tid & 31;
  const int hw  = tid >> 5;             // 0..15

  if (tid < GP_) sse[tid] = ofse[(size_t)tid * NBKT + k];   // strided, 1 instr
  // zero the accumulator tile (1056 floats)
  for (int i = tid; i < TPB * 33; i += 512) ((float*)otile)[i] = 0.0f;
  __syncthreads();

  // scan256 of slice counts -> staging offsets + total
  int v = 0, incl = 0;
  if (tid < GP_) {
    const unsigned u = sse[tid];
    v = (int)(u >> 16) - (int)(u & 0xFFFF);
    incl = v;
#pragma unroll
    for (int off = 1; off < 64; off <<= 1) {
      int uu = __shfl_up(incl, off);
      if ((tid & 63) >= off) incl += uu;
    }
    if ((tid & 63) == 63) wtot4[tid >> 6] = incl;
  }
  __syncthreads();
  if (tid < GP_) {
    int base = 0;
    const int wv = tid >> 6;
    for (int i = 0; i < wv; ++i) base += wtot4[i];
    sstart[tid] = base + incl - v;
  }
  __syncthreads();
  const int total = min(wtot4[0] + wtot4[1] + wtot4[2] + wtot4[3], CAP_SRT);

  // pass 1: read slices (half-wave coalesced) and stage into raw (no hist)
  for (int it = 0; it < 16; ++it) {
    const int g = hw + it * 16;
    const unsigned u = sse[g];
    const int st = (int)(u & 0xFFFF);
    const int n  = (int)(u >> 16) - st;
    const int2* slice = rec + (size_t)g * EPG + st;
    const int lbase = sstart[g];
    for (int j = b; j < n; j += 32) {
      const int idx = lbase + j;
      if (idx < CAP_SRT) raw[idx] = slice[j];
    }
  }
  __syncthreads();

  // pass 2: accumulate. Half-wave hw takes records hw, hw+16, ...; lane = batch.
  // Per record: LDS broadcast read + spikesT line read (L2-hot) + ds_add_f32.
  {
    int i = hw;
    for (; i + 48 < total; i += 64) {
      int2 r0 = raw[i], r1 = raw[i + 16], r2 = raw[i + 32], r3 = raw[i + 48];
      float s0 = spikesT[(size_t)(r0.x & 0x3FFF) * 32 + b];
      float s1 = spikesT[(size_t)(r1.x & 0x3FFF) * 32 + b];
      float s2 = spikesT[(size_t)(r2.x & 0x3FFF) * 32 + b];
      float s3 = spikesT[(size_t)(r3.x & 0x3FFF) * 32 + b];
      atomicAdd(&otile[(r0.x >> 14) & 31][b], __int_as_float(r0.y) * s0);
      atomicAdd(&otile[(r1.x >> 14) & 31][b], __int_as_float(r1.y) * s1);
      atomicAdd(&otile[(r2.x >> 14) & 31][b], __int_as_float(r2.y) * s2);
      atomicAdd(&otile[(r3.x >> 14) & 31][b], __int_as_float(r3.y) * s3);
    }
    for (; i < total; i += 16) {
      int2 r = raw[i];
      float s = spikesT[(size_t)(r.x & 0x3FFF) * 32 + b];
      atomicAdd(&otile[(r.x >> 14) & 31][b], __int_as_float(r.y) * s);
    }
  }
  __syncthreads();

  // write out coalesced (transposed read from otile)
  const int bb = tid >> 4;              // batch 0..31
  const int cc = (tid & 15) * 2;        // target pair
  float2 o2 = make_float2(otile[cc][bb], otile[cc + 1][bb]);
  *reinterpret_cast<float2*>(&out[(size_t)bb * T_ + k * 32 + cc]) = o2;
}

// ---------------------------------------------------------------------------
__global__ void zero_floats(float* __restrict__ p, int n) {
  int i = blockIdx.x * blockDim.x + threadIdx.x;
  if (i < n) p[i] = 0.0f;
}

// Emergency fallback (tiny ws): direct global atomics, weights inline.
__global__ void naive_kernel(const float* __restrict__ spikes,
                             const float* __restrict__ att,
                             const int*   __restrict__ tgt,
                             const int*   __restrict__ del,
                             float*       __restrict__ out) {
  int i = blockIdx.x * blockDim.x + threadIdx.x;
  if (i >= NEDGES) return;
  int   s = i >> 6;
  int   t = tgt[i];
  float w = edge_weight(att[i], del[i]);
  for (int b = 0; b < B_; ++b)
    unsafeAtomicAdd(&out[(size_t)b * T_ + t], w * spikes[(size_t)b * S_ + s]);
}

// ---------------------------------------------------------------------------
extern "C" void kernel_launch(void* const* d_in, const int* in_sizes, int n_in,
                              void* d_out, int out_size, void* d_ws, size_t ws_size,
                              hipStream_t stream) {
  const float* spikes = (const float*)d_in[0];
  const float* att    = (const float*)d_in[1];
  const int*   tgt    = (const int*)d_in[2];
  const int*   del    = (const int*)d_in[3];
  float*       out    = (float*)d_out;

  const size_t spikesT_bytes = (size_t)S_ * B_ * sizeof(float);         // 2 MB
  const size_t rec_bytes     = (size_t)NEDGES * sizeof(int2);           // 8 MB
  const size_t ofse_bytes    = (size_t)GP_ * NBKT * sizeof(unsigned);   // 512 KB
  const size_t need = spikesT_bytes + rec_bytes + ofse_bytes + 64;

  if (ws_size < need) {
    zero_floats<<<(B_ * T_ + 255) / 256, 256, 0, stream>>>(out, B_ * T_);
    naive_kernel<<<(NEDGES + 255) / 256, 256, 0, stream>>>(spikes, att, tgt, del, out);
    return;
  }

  char* p = (char*)d_ws;
  float*        spikesT = (float*)p;        p += spikesT_bytes;
  int2*         rec     = (int2*)p;         p += rec_bytes;
  unsigned int* ofse    = (unsigned int*)p;

  produce<<<GP_, 1024, 0, stream>>>(spikes, att, tgt, del, spikesT, rec, ofse);
  consume<<<NBKT, 512, 0, stream>>>(rec, ofse, spikesT, out);
}

// Round 3
// 255.391 us; speedup vs baseline: 1.0064x; 1.0064x over previous
//
#include <hip/hip_runtime.h>

// Problem constants
#define S_   16384
#define T_   16384
#define B_   32
#define NEDGES (S_ * 64)       // 1,048,576
#define GP_  256               // producer blocks, 4096 edges each
#define EPG  4096              // edges per producer block
#define NBKT 512               // buckets of 32 targets
#define TPB  32                // targets per bucket
#define CAP_SRT 2560           // per-bucket records: lambda=2048, +11 sigma

// weight = clip(att,0,1) * 0.9^delay, delay in [0,6). Exact bit-product.
__device__ __forceinline__ float edge_weight(float a, int d) {
  float w = fminf(fmaxf(a, 0.0f), 1.0f);
  float r = (d & 1) ? 0.9f : 1.0f;
  r = (d & 2) ? r * 0.81f   : r;
  r = (d & 4) ? r * 0.6561f : r;
  return w * r;
}

// ---------------------------------------------------------------------------
// K1: transpose 64 sources of spikes + LDS counting-sort of 4096 edges by
// bucket + ONE contiguous 32 KB flush (full lines, no padding, no spill).
// rec[g][i], i in [0,4096): records {meta = tl<<14 | src, w_bits} grouped by
// bucket; ofse[g][bkt] = end<<16 | start (within-block slice bounds).
__global__ __launch_bounds__(1024) void produce(
    const float* __restrict__ spikes,
    const float* __restrict__ att,
    const int*   __restrict__ tgt,
    const int*   __restrict__ del,
    float*        __restrict__ spikesT,
    int2*         __restrict__ rec,
    unsigned int* __restrict__ ofse) {
  __shared__ float tile[64][33];        // 8.4 KB
  __shared__ int4  sbuf4[EPG / 2];      // 32 KB: 4096 int2 records
  __shared__ int   cnt5[NBKT], cur5[NBKT], sofs5[NBKT];
  __shared__ int   wtot[8];
  int2* buf = (int2*)sbuf4;

  const int g   = blockIdx.x;
  const int tid = threadIdx.x;
  if (tid < NBKT) cnt5[tid] = 0;

  // -- transpose sources [g*64, g*64+64): load half
  const int s0 = g * 64;
  {
    const int x = tid & 63, y = tid >> 6;       // y 0..15
    tile[x][y]      = spikes[(size_t)y        * S_ + s0 + x];
    tile[x][y + 16] = spikes[(size_t)(y + 16) * S_ + s0 + x];
  }

  // -- load my 4 edges (kept in registers across all phases)
  const int e4  = g * 1024 + tid;
  int4   t = reinterpret_cast<const int4*>(tgt)[e4];
  float4 a = reinterpret_cast<const float4*>(att)[e4];
  int4   d = reinterpret_cast<const int4*>(del)[e4];
  const int src = (e4 * 4) >> 6;                // 4 consecutive edges: 1 source

  __syncthreads();                              // cnt5 init + tile visible

  // -- transpose write
  {
    const int b = tid & 31, j = tid >> 5;       // j 0..31
    spikesT[(size_t)(s0 + j)      * 32 + b] = tile[j][b];
    spikesT[(size_t)(s0 + j + 32) * 32 + b] = tile[j + 32][b];
  }

  // -- pass 1: bucket histogram (ds_add, no return needed)
  const int bk0 = t.x >> 5, bk1 = t.y >> 5, bk2 = t.z >> 5, bk3 = t.w >> 5;
  __hip_atomic_fetch_add(&cnt5[bk0], 1, __ATOMIC_RELAXED, __HIP_MEMORY_SCOPE_WORKGROUP);
  __hip_atomic_fetch_add(&cnt5[bk1], 1, __ATOMIC_RELAXED, __HIP_MEMORY_SCOPE_WORKGROUP);
  __hip_atomic_fetch_add(&cnt5[bk2], 1, __ATOMIC_RELAXED, __HIP_MEMORY_SCOPE_WORKGROUP);
  __hip_atomic_fetch_add(&cnt5[bk3], 1, __ATOMIC_RELAXED, __HIP_MEMORY_SCOPE_WORKGROUP);
  __syncthreads();

  // -- exclusive scan of 512 bins: waves 0..7 shuffle-scan 64 each + combine
  int v = 0, incl = 0;
  if (tid < NBKT) {
    v = cnt5[tid];
    incl = v;
#pragma unroll
    for (int off = 1; off < 64; off <<= 1) {
      int u = __shfl_up(incl, off);
      if ((tid & 63) >= off) incl += u;
    }
    if ((tid & 63) == 63) wtot[tid >> 6] = incl;
  }
  __syncthreads();
  if (tid < NBKT) {
    int base = 0;
    const int wv = tid >> 6;
    for (int i = 0; i < wv; ++i) base += wtot[i];
    const int start = base + incl - v;
    sofs5[tid] = start;
    cur5[tid]  = start;
  }
  __syncthreads();

  // -- pass 2: weight + place into LDS at bucket cursor (exact, no overflow)
#define PUT(BK, TL, AV, DV)                                                   \
  {                                                                           \
    int p = __hip_atomic_fetch_add(&cur5[BK], 1, __ATOMIC_RELAXED,            \
                                   __HIP_MEMORY_SCOPE_WORKGROUP);             \
    buf[p] = make_int2(((TL) << 14) | src,                                    \
                       __float_as_int(edge_weight((AV), (DV))));              \
  }
  PUT(bk0, t.x & 31, a.x, d.x)
  PUT(bk1, t.y & 31, a.y, d.y)
  PUT(bk2, t.z & 31, a.z, d.z)
  PUT(bk3, t.w & 31, a.w, d.w)
#undef PUT
  __syncthreads();

  // -- flush: one contiguous 32 KB stream of full lines (int4 x2 per thread)
  int4* recO = reinterpret_cast<int4*>(rec) + (size_t)g * (EPG / 2);
  recO[tid]        = sbuf4[tid];
  recO[tid + 1024] = sbuf4[tid + 1024];
  if (tid < NBKT)
    ofse[(size_t)g * NBKT + tid] =
        ((unsigned)cur5[tid] << 16) | (unsigned)sofs5[tid];   // coalesced
}

// ---------------------------------------------------------------------------
// K2 (v3): single accumulate pass, but with HARDWARE ds_add_f32 via
// unsafeAtomicAdd (plain atomicAdd on LDS floats CAS-loops to preserve
// denormal semantics -> 188us regression in v2; counters: VALUBusy 4.4%,
// waves stalled on LDS round-trips). unsafeAtomicAdd attaches the
// ignore-denormal permission -> real ds_add_f32, conflict-free by the
// (tl+b)%32 bank mapping of the padded otile.
__global__ __launch_bounds__(512) void consume(
    const int2*  __restrict__ rec,
    const unsigned int* __restrict__ ofse,
    const float* __restrict__ spikesT,
    float* __restrict__ out) {
  __shared__ int2  raw[CAP_SRT];        // 20 KB unsorted stage
  __shared__ float otile[TPB][33];      // 4.2 KB accumulator (padded)
  __shared__ unsigned sse[GP_];
  __shared__ int   sstart[GP_];
  __shared__ int   wtot4[4];

  const int k   = blockIdx.x;
  const int tid = threadIdx.x;
  const int b   = tid & 31;
  const int hw  = tid >> 5;             // 0..15

  if (tid < GP_) sse[tid] = ofse[(size_t)tid * NBKT + k];   // strided, 1 instr
  // zero the accumulator tile (1056 floats)
  for (int i = tid; i < TPB * 33; i += 512) ((float*)otile)[i] = 0.0f;
  __syncthreads();

  // scan256 of slice counts -> staging offsets + total
  int v = 0, incl = 0;
  if (tid < GP_) {
    const unsigned u = sse[tid];
    v = (int)(u >> 16) - (int)(u & 0xFFFF);
    incl = v;
#pragma unroll
    for (int off = 1; off < 64; off <<= 1) {
      int uu = __shfl_up(incl, off);
      if ((tid & 63) >= off) incl += uu;
    }
    if ((tid & 63) == 63) wtot4[tid >> 6] = incl;
  }
  __syncthreads();
  if (tid < GP_) {
    int base = 0;
    const int wv = tid >> 6;
    for (int i = 0; i < wv; ++i) base += wtot4[i];
    sstart[tid] = base + incl - v;
  }
  __syncthreads();
  const int total = min(wtot4[0] + wtot4[1] + wtot4[2] + wtot4[3], CAP_SRT);

  // pass 1: read slices (half-wave coalesced) and stage into raw (no hist)
  for (int it = 0; it < 16; ++it) {
    const int g = hw + it * 16;
    const unsigned u = sse[g];
    const int st = (int)(u & 0xFFFF);
    const int n  = (int)(u >> 16) - st;
    const int2* slice = rec + (size_t)g * EPG + st;
    const int lbase = sstart[g];
    for (int j = b; j < n; j += 32) {
      const int idx = lbase + j;
      if (idx < CAP_SRT) raw[idx] = slice[j];
    }
  }
  __syncthreads();

  // pass 2: accumulate. Half-wave hw takes records hw, hw+16, ...; lane = batch.
  // Per record: LDS broadcast read + spikesT line read (L2-hot) + ds_add_f32.
  {
    int i = hw;
    for (; i + 48 < total; i += 64) {
      int2 r0 = raw[i], r1 = raw[i + 16], r2 = raw[i + 32], r3 = raw[i + 48];
      float s0 = spikesT[(size_t)(r0.x & 0x3FFF) * 32 + b];
      float s1 = spikesT[(size_t)(r1.x & 0x3FFF) * 32 + b];
      float s2 = spikesT[(size_t)(r2.x & 0x3FFF) * 32 + b];
      float s3 = spikesT[(size_t)(r3.x & 0x3FFF) * 32 + b];
      unsafeAtomicAdd(&otile[(r0.x >> 14) & 31][b], __int_as_float(r0.y) * s0);
      unsafeAtomicAdd(&otile[(r1.x >> 14) & 31][b], __int_as_float(r1.y) * s1);
      unsafeAtomicAdd(&otile[(r2.x >> 14) & 31][b], __int_as_float(r2.y) * s2);
      unsafeAtomicAdd(&otile[(r3.x >> 14) & 31][b], __int_as_float(r3.y) * s3);
    }
    for (; i < total; i += 16) {
      int2 r = raw[i];
      float s = spikesT[(size_t)(r.x & 0x3FFF) * 32 + b];
      unsafeAtomicAdd(&otile[(r.x >> 14) & 31][b], __int_as_float(r.y) * s);
    }
  }
  __syncthreads();

  // write out coalesced (transposed read from otile)
  const int bb = tid >> 4;              // batch 0..31
  const int cc = (tid & 15) * 2;        // target pair
  float2 o2 = make_float2(otile[cc][bb], otile[cc + 1][bb]);
  *reinterpret_cast<float2*>(&out[(size_t)bb * T_ + k * 32 + cc]) = o2;
}

// ---------------------------------------------------------------------------
__global__ void zero_floats(float* __restrict__ p, int n) {
  int i = blockIdx.x * blockDim.x + threadIdx.x;
  if (i < n) p[i] = 0.0f;
}

// Emergency fallback (tiny ws): direct global atomics, weights inline.
__global__ void naive_kernel(const float* __restrict__ spikes,
                             const float* __restrict__ att,
                             const int*   __restrict__ tgt,
                             const int*   __restrict__ del,
                             float*       __restrict__ out) {
  int i = blockIdx.x * blockDim.x + threadIdx.x;
  if (i >= NEDGES) return;
  int   s = i >> 6;
  int   t = tgt[i];
  float w = edge_weight(att[i], del[i]);
  for (int b = 0; b < B_; ++b)
    unsafeAtomicAdd(&out[(size_t)b * T_ + t], w * spikes[(size_t)b * S_ + s]);
}

// ---------------------------------------------------------------------------
extern "C" void kernel_launch(void* const* d_in, const int* in_sizes, int n_in,
                              void* d_out, int out_size, void* d_ws, size_t ws_size,
                              hipStream_t stream) {
  const float* spikes = (const float*)d_in[0];
  const float* att    = (const float*)d_in[1];
  const int*   tgt    = (const int*)d_in[2];
  const int*   del    = (const int*)d_in[3];
  float*       out    = (float*)d_out;

  const size_t spikesT_bytes = (size_t)S_ * B_ * sizeof(float);         // 2 MB
  const size_t rec_bytes     = (size_t)NEDGES * sizeof(int2);           // 8 MB
  const size_t ofse_bytes    = (size_t)GP_ * NBKT * sizeof(unsigned);   // 512 KB
  const size_t need = spikesT_bytes + rec_bytes + ofse_bytes + 64;

  if (ws_size < need) {
    zero_floats<<<(B_ * T_ + 255) / 256, 256, 0, stream>>>(out, B_ * T_);
    naive_kernel<<<(NEDGES + 255) / 256, 256, 0, stream>>>(spikes, att, tgt, del, out);
    return;
  }

  char* p = (char*)d_ws;
  float*        spikesT = (float*)p;        p += spikesT_bytes;
  int2*         rec     = (int2*)p;         p += rec_bytes;
  unsigned int* ofse    = (unsigned int*)p;

  produce<<<GP_, 1024, 0, stream>>>(spikes, att, tgt, del, spikesT, rec, ofse);
  consume<<<NBKT, 512, 0, stream>>>(rec, ofse, spikesT, out);
}

// Round 4
// 91.082 us; speedup vs baseline: 2.8220x; 2.8040x over previous
//
#include <hip/hip_runtime.h>

// Problem constants
#define S_   16384
#define T_   16384
#define B_   32
#define NEDGES (S_ * 64)       // 1,048,576
#define GP_  256               // producer blocks, 4096 edges each
#define EPG  4096              // edges per producer block
#define NBKT 512               // buckets of 32 targets
#define TPB  32                // targets per bucket
#define CAP_SRT 2560           // per-bucket records: lambda=2048, +11 sigma

// weight = clip(att,0,1) * 0.9^delay, delay in [0,6). Exact bit-product.
__device__ __forceinline__ float edge_weight(float a, int d) {
  float w = fminf(fmaxf(a, 0.0f), 1.0f);
  float r = (d & 1) ? 0.9f : 1.0f;
  r = (d & 2) ? r * 0.81f   : r;
  r = (d & 4) ? r * 0.6561f : r;
  return w * r;
}

// ---------------------------------------------------------------------------
// K1: transpose 64 sources of spikes + LDS counting-sort of 4096 edges by
// bucket + ONE contiguous 32 KB flush (full lines, no padding, no spill).
// rec[g][i], i in [0,4096): records {meta = tl<<14 | src, w_bits} grouped by
// bucket; ofse[g][bkt] = end<<16 | start (within-block slice bounds).
__global__ __launch_bounds__(1024) void produce(
    const float* __restrict__ spikes,
    const float* __restrict__ att,
    const int*   __restrict__ tgt,
    const int*   __restrict__ del,
    float*        __restrict__ spikesT,
    int2*         __restrict__ rec,
    unsigned int* __restrict__ ofse) {
  __shared__ float tile[64][33];        // 8.4 KB
  __shared__ int4  sbuf4[EPG / 2];      // 32 KB: 4096 int2 records
  __shared__ int   cnt5[NBKT], cur5[NBKT], sofs5[NBKT];
  __shared__ int   wtot[8];
  int2* buf = (int2*)sbuf4;

  const int g   = blockIdx.x;
  const int tid = threadIdx.x;
  if (tid < NBKT) cnt5[tid] = 0;

  // -- transpose sources [g*64, g*64+64): load half
  const int s0 = g * 64;
  {
    const int x = tid & 63, y = tid >> 6;       // y 0..15
    tile[x][y]      = spikes[(size_t)y        * S_ + s0 + x];
    tile[x][y + 16] = spikes[(size_t)(y + 16) * S_ + s0 + x];
  }

  // -- load my 4 edges (kept in registers across all phases)
  const int e4  = g * 1024 + tid;
  int4   t = reinterpret_cast<const int4*>(tgt)[e4];
  float4 a = reinterpret_cast<const float4*>(att)[e4];
  int4   d = reinterpret_cast<const int4*>(del)[e4];
  const int src = (e4 * 4) >> 6;                // 4 consecutive edges: 1 source

  __syncthreads();                              // cnt5 init + tile visible

  // -- transpose write
  {
    const int b = tid & 31, j = tid >> 5;       // j 0..31
    spikesT[(size_t)(s0 + j)      * 32 + b] = tile[j][b];
    spikesT[(size_t)(s0 + j + 32) * 32 + b] = tile[j + 32][b];
  }

  // -- pass 1: bucket histogram (ds_add, no return needed)
  const int bk0 = t.x >> 5, bk1 = t.y >> 5, bk2 = t.z >> 5, bk3 = t.w >> 5;
  __hip_atomic_fetch_add(&cnt5[bk0], 1, __ATOMIC_RELAXED, __HIP_MEMORY_SCOPE_WORKGROUP);
  __hip_atomic_fetch_add(&cnt5[bk1], 1, __ATOMIC_RELAXED, __HIP_MEMORY_SCOPE_WORKGROUP);
  __hip_atomic_fetch_add(&cnt5[bk2], 1, __ATOMIC_RELAXED, __HIP_MEMORY_SCOPE_WORKGROUP);
  __hip_atomic_fetch_add(&cnt5[bk3], 1, __ATOMIC_RELAXED, __HIP_MEMORY_SCOPE_WORKGROUP);
  __syncthreads();

  // -- exclusive scan of 512 bins: waves 0..7 shuffle-scan 64 each + combine
  int v = 0, incl = 0;
  if (tid < NBKT) {
    v = cnt5[tid];
    incl = v;
#pragma unroll
    for (int off = 1; off < 64; off <<= 1) {
      int u = __shfl_up(incl, off);
      if ((tid & 63) >= off) incl += u;
    }
    if ((tid & 63) == 63) wtot[tid >> 6] = incl;
  }
  __syncthreads();
  if (tid < NBKT) {
    int base = 0;
    const int wv = tid >> 6;
    for (int i = 0; i < wv; ++i) base += wtot[i];
    const int start = base + incl - v;
    sofs5[tid] = start;
    cur5[tid]  = start;
  }
  __syncthreads();

  // -- pass 2: weight + place into LDS at bucket cursor (exact, no overflow)
#define PUT(BK, TL, AV, DV)                                                   \
  {                                                                           \
    int p = __hip_atomic_fetch_add(&cur5[BK], 1, __ATOMIC_RELAXED,            \
                                   __HIP_MEMORY_SCOPE_WORKGROUP);             \
    buf[p] = make_int2(((TL) << 14) | src,                                    \
                       __float_as_int(edge_weight((AV), (DV))));              \
  }
  PUT(bk0, t.x & 31, a.x, d.x)
  PUT(bk1, t.y & 31, a.y, d.y)
  PUT(bk2, t.z & 31, a.z, d.z)
  PUT(bk3, t.w & 31, a.w, d.w)
#undef PUT
  __syncthreads();

  // -- flush: one contiguous 32 KB stream of full lines (int4 x2 per thread)
  int4* recO = reinterpret_cast<int4*>(rec) + (size_t)g * (EPG / 2);
  recO[tid]        = sbuf4[tid];
  recO[tid + 1024] = sbuf4[tid + 1024];
  if (tid < NBKT)
    ofse[(size_t)g * NBKT + tid] =
        ((unsigned)cur5[tid] << 16) | (unsigned)sofs5[tid];   // coalesced
}

// ---------------------------------------------------------------------------
// K2 (v4 = v1 sorted-gather, with ONE change): pass-1 staging uses 8 lanes
// per slice (avg slice length n~=8) instead of 32 -> 64 slices in flight per
// iteration, outer sequential depth 16 -> 4, same 64B transactions, 4x
// memory-level parallelism. Sort passes + register gather identical to the
// 93.9us-verified v1. (LDS atomic-accumulate variants measured 188us:
// ~350cy/record latency-serialized, VALUBusy 4.4% -- abandoned.)
__global__ __launch_bounds__(512) void consume(
    const int2*  __restrict__ rec,
    const unsigned int* __restrict__ ofse,
    const float* __restrict__ spikesT,
    float* __restrict__ out) {
  __shared__ int2  raw[CAP_SRT];        // 20 KB unsorted stage
  __shared__ int2  srt[CAP_SRT];        // 20 KB target-sorted
  __shared__ float otile[TPB][33];      // 4.2 KB
  __shared__ unsigned sse[GP_];
  __shared__ int   sstart[GP_];
  __shared__ int   wtot4[4];
  __shared__ int   h32[TPB], ofs[TPB + 1], cur32[TPB];

  const int k   = blockIdx.x;
  const int tid = threadIdx.x;
  const int b   = tid & 31;
  const int hw  = tid >> 5;             // 0..15

  if (tid < TPB) h32[tid] = 0;
  if (tid < GP_) sse[tid] = ofse[(size_t)tid * NBKT + k];   // strided, 1 instr
  __syncthreads();

  // scan256 of slice counts -> staging offsets + total
  int v = 0, incl = 0;
  if (tid < GP_) {
    const unsigned u = sse[tid];
    v = (int)(u >> 16) - (int)(u & 0xFFFF);
    incl = v;
#pragma unroll
    for (int off = 1; off < 64; off <<= 1) {
      int uu = __shfl_up(incl, off);
      if ((tid & 63) >= off) incl += uu;
    }
    if ((tid & 63) == 63) wtot4[tid >> 6] = incl;
  }
  __syncthreads();
  if (tid < GP_) {
    int base = 0;
    const int wv = tid >> 6;
    for (int i = 0; i < wv; ++i) base += wtot4[i];
    sstart[tid] = base + incl - v;
  }
  __syncthreads();
  const int total = min(wtot4[0] + wtot4[1] + wtot4[2] + wtot4[3], CAP_SRT);

  // pass 1: 8 lanes per slice, 64 slices concurrent, 4 outer iterations.
  {
    const int grp = tid >> 3;           // 0..63
    const int l8  = tid & 7;
    for (int it = 0; it < 4; ++it) {
      const int g = grp + it * 64;
      const unsigned u = sse[g];
      const int st = (int)(u & 0xFFFF);
      const int n  = (int)(u >> 16) - st;
      const int2* slice = rec + (size_t)g * EPG + st;
      const int lbase = sstart[g];
      for (int j = l8; j < n; j += 8) {
        int2 r = slice[j];
        __hip_atomic_fetch_add(&h32[(r.x >> 14) & 31], 1, __ATOMIC_RELAXED,
                               __HIP_MEMORY_SCOPE_WORKGROUP);
        const int idx = lbase + j;
        if (idx < CAP_SRT) raw[idx] = r;
      }
    }
  }
  __syncthreads();

  // scan32 of target bins (wave 0)
  if (tid < 32) {
    int vv = h32[tid], ii = vv;
#pragma unroll
    for (int off = 1; off < 32; off <<= 1) {
      int uu = __shfl_up(ii, off);
      if (tid >= off) ii += uu;
    }
    ofs[tid]   = ii - vv;
    cur32[tid] = ii - vv;
    if (tid == 31) ofs[32] = ii;
  }
  __syncthreads();

  // pass 2: rank + scatter raw -> srt (LDS only)
  for (int i = tid; i < total; i += 512) {
    int2 r = raw[i];
    int p = __hip_atomic_fetch_add(&cur32[(r.x >> 14) & 31], 1,
                                   __ATOMIC_RELAXED,
                                   __HIP_MEMORY_SCOPE_WORKGROUP);
    if (p < CAP_SRT) srt[p] = r;
  }
  __syncthreads();

  // gather: half-wave hw owns targets hw (acc0), hw+16 (acc1); lane = batch
  float acc0 = 0.f, acc1 = 0.f;
  {
    int e        = ofs[hw];
    const int e1 = min(ofs[hw + 1], total);
    for (; e + 4 <= e1; e += 4) {
      int2 r0 = srt[e], r1 = srt[e + 1], r2 = srt[e + 2], r3 = srt[e + 3];
      float s0 = spikesT[(size_t)(r0.x & 0x3FFF) * 32 + b];
      float s1 = spikesT[(size_t)(r1.x & 0x3FFF) * 32 + b];
      float s2 = spikesT[(size_t)(r2.x & 0x3FFF) * 32 + b];
      float s3 = spikesT[(size_t)(r3.x & 0x3FFF) * 32 + b];
      acc0 = fmaf(__int_as_float(r0.y), s0, acc0);
      acc0 = fmaf(__int_as_float(r1.y), s1, acc0);
      acc0 = fmaf(__int_as_float(r2.y), s2, acc0);
      acc0 = fmaf(__int_as_float(r3.y), s3, acc0);
    }
    for (; e < e1; ++e) {
      int2 r = srt[e];
      acc0 = fmaf(__int_as_float(r.y), spikesT[(size_t)(r.x & 0x3FFF) * 32 + b], acc0);
    }
  }
  {
    int e        = ofs[hw + 16];
    const int e1 = min(ofs[hw + 17], total);
    for (; e + 4 <= e1; e += 4) {
      int2 r0 = srt[e], r1 = srt[e + 1], r2 = srt[e + 2], r3 = srt[e + 3];
      float s0 = spikesT[(size_t)(r0.x & 0x3FFF) * 32 + b];
      float s1 = spikesT[(size_t)(r1.x & 0x3FFF) * 32 + b];
      float s2 = spikesT[(size_t)(r2.x & 0x3FFF) * 32 + b];
      float s3 = spikesT[(size_t)(r3.x & 0x3FFF) * 32 + b];
      acc1 = fmaf(__int_as_float(r0.y), s0, acc1);
      acc1 = fmaf(__int_as_float(r1.y), s1, acc1);
      acc1 = fmaf(__int_as_float(r2.y), s2, acc1);
      acc1 = fmaf(__int_as_float(r3.y), s3, acc1);
    }
    for (; e < e1; ++e) {
      int2 r = srt[e];
      acc1 = fmaf(__int_as_float(r.y), spikesT[(size_t)(r.x & 0x3FFF) * 32 + b], acc1);
    }
  }

  // transpose 32x32 tile and write out coalesced
  otile[hw][b]      = acc0;
  otile[hw + 16][b] = acc1;
  __syncthreads();
  const int bb = tid >> 4;              // batch 0..31
  const int cc = (tid & 15) * 2;        // target pair
  float2 o2 = make_float2(otile[cc][bb], otile[cc + 1][bb]);
  *reinterpret_cast<float2*>(&out[(size_t)bb * T_ + k * 32 + cc]) = o2;
}

// ---------------------------------------------------------------------------
__global__ void zero_floats(float* __restrict__ p, int n) {
  int i = blockIdx.x * blockDim.x + threadIdx.x;
  if (i < n) p[i] = 0.0f;
}

// Emergency fallback (tiny ws): direct global atomics, weights inline.
__global__ void naive_kernel(const float* __restrict__ spikes,
                             const float* __restrict__ att,
                             const int*   __restrict__ tgt,
                             const int*   __restrict__ del,
                             float*       __restrict__ out) {
  int i = blockIdx.x * blockDim.x + threadIdx.x;
  if (i >= NEDGES) return;
  int   s = i >> 6;
  int   t = tgt[i];
  float w = edge_weight(att[i], del[i]);
  for (int b = 0; b < B_; ++b)
    unsafeAtomicAdd(&out[(size_t)b * T_ + t], w * spikes[(size_t)b * S_ + s]);
}

// ---------------------------------------------------------------------------
extern "C" void kernel_launch(void* const* d_in, const int* in_sizes, int n_in,
                              void* d_out, int out_size, void* d_ws, size_t ws_size,
                              hipStream_t stream) {
  const float* spikes = (const float*)d_in[0];
  const float* att    = (const float*)d_in[1];
  const int*   tgt    = (const int*)d_in[2];
  const int*   del    = (const int*)d_in[3];
  float*       out    = (float*)d_out;

  const size_t spikesT_bytes = (size_t)S_ * B_ * sizeof(float);         // 2 MB
  const size_t rec_bytes     = (size_t)NEDGES * sizeof(int2);           // 8 MB
  const size_t ofse_bytes    = (size_t)GP_ * NBKT * sizeof(unsigned);   // 512 KB
  const size_t need = spikesT_bytes + rec_bytes + ofse_bytes + 64;

  if (ws_size < need) {
    zero_floats<<<(B_ * T_ + 255) / 256, 256, 0, stream>>>(out, B_ * T_);
    naive_kernel<<<(NEDGES + 255) / 256, 256, 0, stream>>>(spikes, att, tgt, del, out);
    return;
  }

  char* p = (char*)d_ws;
  float*        spikesT = (float*)p;        p += spikesT_bytes;
  int2*         rec     = (int2*)p;         p += rec_bytes;
  unsigned int* ofse    = (unsigned int*)p;

  produce<<<GP_, 1024, 0, stream>>>(spikes, att, tgt, del, spikesT, rec, ofse);
  consume<<<NBKT, 512, 0, stream>>>(rec, ofse, spikesT, out);
}

// Round 5
// 88.791 us; speedup vs baseline: 2.8949x; 1.0258x over previous
//
#include <hip/hip_runtime.h>

// Problem constants
#define S_   16384
#define T_   16384
#define B_   32
#define NEDGES (S_ * 64)       // 1,048,576
#define GP_  256               // producer blocks, 4096 edges each
#define EPG  4096              // edges per producer block
#define NBKT 512               // buckets of 32 targets
#define TPB  32                // targets per bucket
#define CAP_SRT 2560           // per-bucket records: lambda=2048, +11 sigma

// weight = clip(att,0,1) * 0.9^delay, delay in [0,6). Exact bit-product.
__device__ __forceinline__ float edge_weight(float a, int d) {
  float w = fminf(fmaxf(a, 0.0f), 1.0f);
  float r = (d & 1) ? 0.9f : 1.0f;
  r = (d & 2) ? r * 0.81f   : r;
  r = (d & 4) ? r * 0.6561f : r;
  return w * r;
}

// ---------------------------------------------------------------------------
// K1: transpose 64 sources of spikes + LDS counting-sort of 4096 edges by
// bucket + ONE contiguous 32 KB flush (full lines, no padding, no spill).
// rec[g][i], i in [0,4096): records {meta = tl<<14 | src, w_bits} grouped by
// bucket; ofse[g][bkt] = end<<16 | start (within-block slice bounds).
__global__ __launch_bounds__(1024) void produce(
    const float* __restrict__ spikes,
    const float* __restrict__ att,
    const int*   __restrict__ tgt,
    const int*   __restrict__ del,
    float*        __restrict__ spikesT,
    int2*         __restrict__ rec,
    unsigned int* __restrict__ ofse) {
  __shared__ float tile[64][33];        // 8.4 KB
  __shared__ int4  sbuf4[EPG / 2];      // 32 KB: 4096 int2 records
  __shared__ int   cnt5[NBKT], cur5[NBKT], sofs5[NBKT];
  __shared__ int   wtot[8];
  int2* buf = (int2*)sbuf4;

  const int g   = blockIdx.x;
  const int tid = threadIdx.x;
  if (tid < NBKT) cnt5[tid] = 0;

  // -- transpose sources [g*64, g*64+64): load half
  const int s0 = g * 64;
  {
    const int x = tid & 63, y = tid >> 6;       // y 0..15
    tile[x][y]      = spikes[(size_t)y        * S_ + s0 + x];
    tile[x][y + 16] = spikes[(size_t)(y + 16) * S_ + s0 + x];
  }

  // -- load my 4 edges (kept in registers across all phases)
  const int e4  = g * 1024 + tid;
  int4   t = reinterpret_cast<const int4*>(tgt)[e4];
  float4 a = reinterpret_cast<const float4*>(att)[e4];
  int4   d = reinterpret_cast<const int4*>(del)[e4];
  const int src = (e4 * 4) >> 6;                // 4 consecutive edges: 1 source

  __syncthreads();                              // cnt5 init + tile visible

  // -- transpose write
  {
    const int b = tid & 31, j = tid >> 5;       // j 0..31
    spikesT[(size_t)(s0 + j)      * 32 + b] = tile[j][b];
    spikesT[(size_t)(s0 + j + 32) * 32 + b] = tile[j + 32][b];
  }

  // -- pass 1: bucket histogram (ds_add, no return needed)
  const int bk0 = t.x >> 5, bk1 = t.y >> 5, bk2 = t.z >> 5, bk3 = t.w >> 5;
  __hip_atomic_fetch_add(&cnt5[bk0], 1, __ATOMIC_RELAXED, __HIP_MEMORY_SCOPE_WORKGROUP);
  __hip_atomic_fetch_add(&cnt5[bk1], 1, __ATOMIC_RELAXED, __HIP_MEMORY_SCOPE_WORKGROUP);
  __hip_atomic_fetch_add(&cnt5[bk2], 1, __ATOMIC_RELAXED, __HIP_MEMORY_SCOPE_WORKGROUP);
  __hip_atomic_fetch_add(&cnt5[bk3], 1, __ATOMIC_RELAXED, __HIP_MEMORY_SCOPE_WORKGROUP);
  __syncthreads();

  // -- exclusive scan of 512 bins: waves 0..7 shuffle-scan 64 each + combine
  int v = 0, incl = 0;
  if (tid < NBKT) {
    v = cnt5[tid];
    incl = v;
#pragma unroll
    for (int off = 1; off < 64; off <<= 1) {
      int u = __shfl_up(incl, off);
      if ((tid & 63) >= off) incl += u;
    }
    if ((tid & 63) == 63) wtot[tid >> 6] = incl;
  }
  __syncthreads();
  if (tid < NBKT) {
    int base = 0;
    const int wv = tid >> 6;
    for (int i = 0; i < wv; ++i) base += wtot[i];
    const int start = base + incl - v;
    sofs5[tid] = start;
    cur5[tid]  = start;
  }
  __syncthreads();

  // -- pass 2: weight + place into LDS at bucket cursor (exact, no overflow)
#define PUT(BK, TL, AV, DV)                                                   \
  {                                                                           \
    int p = __hip_atomic_fetch_add(&cur5[BK], 1, __ATOMIC_RELAXED,            \
                                   __HIP_MEMORY_SCOPE_WORKGROUP);             \
    buf[p] = make_int2(((TL) << 14) | src,                                    \
                       __float_as_int(edge_weight((AV), (DV))));              \
  }
  PUT(bk0, t.x & 31, a.x, d.x)
  PUT(bk1, t.y & 31, a.y, d.y)
  PUT(bk2, t.z & 31, a.z, d.z)
  PUT(bk3, t.w & 31, a.w, d.w)
#undef PUT
  __syncthreads();

  // -- flush: one contiguous 32 KB stream of full lines (int4 x2 per thread)
  int4* recO = reinterpret_cast<int4*>(rec) + (size_t)g * (EPG / 2);
  recO[tid]        = sbuf4[tid];
  recO[tid + 1024] = sbuf4[tid + 1024];
  if (tid < NBKT)
    ofse[(size_t)g * NBKT + tid] =
        ((unsigned)cur5[tid] << 16) | (unsigned)sofs5[tid];   // coalesced
}

// ---------------------------------------------------------------------------
// K2 (v5 = v4 + interleaved gather): the two per-half-wave target loops are
// fused so 8 spikesT loads + 8 srt reads are in flight per batch (VGPR was
// 12 -- pure latency bind, huge register headroom). Pass 1 staging: 8 lanes
// per slice, 64 slices in flight. Sort passes identical to 93.9us v1.
__global__ __launch_bounds__(512) void consume(
    const int2*  __restrict__ rec,
    const unsigned int* __restrict__ ofse,
    const float* __restrict__ spikesT,
    float* __restrict__ out) {
  __shared__ int2  raw[CAP_SRT];        // 20 KB unsorted stage
  __shared__ int2  srt[CAP_SRT];        // 20 KB target-sorted
  __shared__ float otile[TPB][33];      // 4.2 KB
  __shared__ unsigned sse[GP_];
  __shared__ int   sstart[GP_];
  __shared__ int   wtot4[4];
  __shared__ int   h32[TPB], ofs[TPB + 1], cur32[TPB];

  const int k   = blockIdx.x;
  const int tid = threadIdx.x;
  const int b   = tid & 31;
  const int hw  = tid >> 5;             // 0..15

  if (tid < TPB) h32[tid] = 0;
  if (tid < GP_) sse[tid] = ofse[(size_t)tid * NBKT + k];   // strided, 1 instr
  __syncthreads();

  // scan256 of slice counts -> staging offsets + total
  int v = 0, incl = 0;
  if (tid < GP_) {
    const unsigned u = sse[tid];
    v = (int)(u >> 16) - (int)(u & 0xFFFF);
    incl = v;
#pragma unroll
    for (int off = 1; off < 64; off <<= 1) {
      int uu = __shfl_up(incl, off);
      if ((tid & 63) >= off) incl += uu;
    }
    if ((tid & 63) == 63) wtot4[tid >> 6] = incl;
  }
  __syncthreads();
  if (tid < GP_) {
    int base = 0;
    const int wv = tid >> 6;
    for (int i = 0; i < wv; ++i) base += wtot4[i];
    sstart[tid] = base + incl - v;
  }
  __syncthreads();
  const int total = min(wtot4[0] + wtot4[1] + wtot4[2] + wtot4[3], CAP_SRT);

  // pass 1: 8 lanes per slice, 64 slices concurrent, 4 outer iterations.
  {
    const int grp = tid >> 3;           // 0..63
    const int l8  = tid & 7;
    for (int it = 0; it < 4; ++it) {
      const int g = grp + it * 64;
      const unsigned u = sse[g];
      const int st = (int)(u & 0xFFFF);
      const int n  = (int)(u >> 16) - st;
      const int2* slice = rec + (size_t)g * EPG + st;
      const int lbase = sstart[g];
      for (int j = l8; j < n; j += 8) {
        int2 r = slice[j];
        __hip_atomic_fetch_add(&h32[(r.x >> 14) & 31], 1, __ATOMIC_RELAXED,
                               __HIP_MEMORY_SCOPE_WORKGROUP);
        const int idx = lbase + j;
        if (idx < CAP_SRT) raw[idx] = r;
      }
    }
  }
  __syncthreads();

  // scan32 of target bins (wave 0)
  if (tid < 32) {
    int vv = h32[tid], ii = vv;
#pragma unroll
    for (int off = 1; off < 32; off <<= 1) {
      int uu = __shfl_up(ii, off);
      if (tid >= off) ii += uu;
    }
    ofs[tid]   = ii - vv;
    cur32[tid] = ii - vv;
    if (tid == 31) ofs[32] = ii;
  }
  __syncthreads();

  // pass 2: rank + scatter raw -> srt (LDS only)
  for (int i = tid; i < total; i += 512) {
    int2 r = raw[i];
    int p = __hip_atomic_fetch_add(&cur32[(r.x >> 14) & 31], 1,
                                   __ATOMIC_RELAXED,
                                   __HIP_MEMORY_SCOPE_WORKGROUP);
    if (p < CAP_SRT) srt[p] = r;
  }
  __syncthreads();

  // gather: half-wave hw owns targets hw (acc0) and hw+16 (acc1); lane=batch.
  // INTERLEAVED: 4 records of each target per batch -> 8 srt reads + 8
  // spikesT loads outstanding, halving the serial dependent-batch count.
  float acc0 = 0.f, acc1 = 0.f;
  int e0 = ofs[hw];
  int e1 = ofs[hw + 16];
  const int e0e = min(ofs[hw + 1],  total);
  const int e1e = min(ofs[hw + 17], total);

  for (; e0 + 4 <= e0e && e1 + 4 <= e1e; e0 += 4, e1 += 4) {
    int2 r0 = srt[e0], r1 = srt[e0 + 1], r2 = srt[e0 + 2], r3 = srt[e0 + 3];
    int2 q0 = srt[e1], q1 = srt[e1 + 1], q2 = srt[e1 + 2], q3 = srt[e1 + 3];
    float s0 = spikesT[(size_t)(r0.x & 0x3FFF) * 32 + b];
    float s1 = spikesT[(size_t)(r1.x & 0x3FFF) * 32 + b];
    float s2 = spikesT[(size_t)(r2.x & 0x3FFF) * 32 + b];
    float s3 = spikesT[(size_t)(r3.x & 0x3FFF) * 32 + b];
    float u0 = spikesT[(size_t)(q0.x & 0x3FFF) * 32 + b];
    float u1 = spikesT[(size_t)(q1.x & 0x3FFF) * 32 + b];
    float u2 = spikesT[(size_t)(q2.x & 0x3FFF) * 32 + b];
    float u3 = spikesT[(size_t)(q3.x & 0x3FFF) * 32 + b];
    acc0 = fmaf(__int_as_float(r0.y), s0, acc0);
    acc0 = fmaf(__int_as_float(r1.y), s1, acc0);
    acc0 = fmaf(__int_as_float(r2.y), s2, acc0);
    acc0 = fmaf(__int_as_float(r3.y), s3, acc0);
    acc1 = fmaf(__int_as_float(q0.y), u0, acc1);
    acc1 = fmaf(__int_as_float(q1.y), u1, acc1);
    acc1 = fmaf(__int_as_float(q2.y), u2, acc1);
    acc1 = fmaf(__int_as_float(q3.y), u3, acc1);
  }
  // drain target A
  for (; e0 + 4 <= e0e; e0 += 4) {
    int2 r0 = srt[e0], r1 = srt[e0 + 1], r2 = srt[e0 + 2], r3 = srt[e0 + 3];
    float s0 = spikesT[(size_t)(r0.x & 0x3FFF) * 32 + b];
    float s1 = spikesT[(size_t)(r1.x & 0x3FFF) * 32 + b];
    float s2 = spikesT[(size_t)(r2.x & 0x3FFF) * 32 + b];
    float s3 = spikesT[(size_t)(r3.x & 0x3FFF) * 32 + b];
    acc0 = fmaf(__int_as_float(r0.y), s0, acc0);
    acc0 = fmaf(__int_as_float(r1.y), s1, acc0);
    acc0 = fmaf(__int_as_float(r2.y), s2, acc0);
    acc0 = fmaf(__int_as_float(r3.y), s3, acc0);
  }
  for (; e0 < e0e; ++e0) {
    int2 r = srt[e0];
    acc0 = fmaf(__int_as_float(r.y), spikesT[(size_t)(r.x & 0x3FFF) * 32 + b], acc0);
  }
  // drain target B
  for (; e1 + 4 <= e1e; e1 += 4) {
    int2 q0 = srt[e1], q1 = srt[e1 + 1], q2 = srt[e1 + 2], q3 = srt[e1 + 3];
    float u0 = spikesT[(size_t)(q0.x & 0x3FFF) * 32 + b];
    float u1 = spikesT[(size_t)(q1.x & 0x3FFF) * 32 + b];
    float u2 = spikesT[(size_t)(q2.x & 0x3FFF) * 32 + b];
    float u3 = spikesT[(size_t)(q3.x & 0x3FFF) * 32 + b];
    acc1 = fmaf(__int_as_float(q0.y), u0, acc1);
    acc1 = fmaf(__int_as_float(q1.y), u1, acc1);
    acc1 = fmaf(__int_as_float(q2.y), u2, acc1);
    acc1 = fmaf(__int_as_float(q3.y), u3, acc1);
  }
  for (; e1 < e1e; ++e1) {
    int2 q = srt[e1];
    acc1 = fmaf(__int_as_float(q.y), spikesT[(size_t)(q.x & 0x3FFF) * 32 + b], acc1);
  }

  // transpose 32x32 tile and write out coalesced
  otile[hw][b]      = acc0;
  otile[hw + 16][b] = acc1;
  __syncthreads();
  const int bb = tid >> 4;              // batch 0..31
  const int cc = (tid & 15) * 2;        // target pair
  float2 o2 = make_float2(otile[cc][bb], otile[cc + 1][bb]);
  *reinterpret_cast<float2*>(&out[(size_t)bb * T_ + k * 32 + cc]) = o2;
}

// ---------------------------------------------------------------------------
__global__ void zero_floats(float* __restrict__ p, int n) {
  int i = blockIdx.x * blockDim.x + threadIdx.x;
  if (i < n) p[i] = 0.0f;
}

// Emergency fallback (tiny ws): direct global atomics, weights inline.
__global__ void naive_kernel(const float* __restrict__ spikes,
                             const float* __restrict__ att,
                             const int*   __restrict__ tgt,
                             const int*   __restrict__ del,
                             float*       __restrict__ out) {
  int i = blockIdx.x * blockDim.x + threadIdx.x;
  if (i >= NEDGES) return;
  int   s = i >> 6;
  int   t = tgt[i];
  float w = edge_weight(att[i], del[i]);
  for (int b = 0; b < B_; ++b)
    unsafeAtomicAdd(&out[(size_t)b * T_ + t], w * spikes[(size_t)b * S_ + s]);
}

// ---------------------------------------------------------------------------
extern "C" void kernel_launch(void* const* d_in, const int* in_sizes, int n_in,
                              void* d_out, int out_size, void* d_ws, size_t ws_size,
                              hipStream_t stream) {
  const float* spikes = (const float*)d_in[0];
  const float* att    = (const float*)d_in[1];
  const int*   tgt    = (const int*)d_in[2];
  const int*   del    = (const int*)d_in[3];
  float*       out    = (float*)d_out;

  const size_t spikesT_bytes = (size_t)S_ * B_ * sizeof(float);         // 2 MB
  const size_t rec_bytes     = (size_t)NEDGES * sizeof(int2);           // 8 MB
  const size_t ofse_bytes    = (size_t)GP_ * NBKT * sizeof(unsigned);   // 512 KB
  const size_t need = spikesT_bytes + rec_bytes + ofse_bytes + 64;

  if (ws_size < need) {
    zero_floats<<<(B_ * T_ + 255) / 256, 256, 0, stream>>>(out, B_ * T_);
    naive_kernel<<<(NEDGES + 255) / 256, 256, 0, stream>>>(spikes, att, tgt, del, out);
    return;
  }

  char* p = (char*)d_ws;
  float*        spikesT = (float*)p;        p += spikesT_bytes;
  int2*         rec     = (int2*)p;         p += rec_bytes;
  unsigned int* ofse    = (unsigned int*)p;

  produce<<<GP_, 1024, 0, stream>>>(spikes, att, tgt, del, spikesT, rec, ofse);
  consume<<<NBKT, 512, 0, stream>>>(rec, ofse, spikesT, out);
}

// Round 6
// 88.235 us; speedup vs baseline: 2.9131x; 1.0063x over previous
//
#include <hip/hip_runtime.h>

// Problem constants
#define S_   16384
#define T_   16384
#define B_   32
#define NEDGES (S_ * 64)       // 1,048,576
#define GP_  256               // producer blocks, 4096 edges each
#define EPG  4096              // edges per producer block
#define NBKT 512               // buckets of 32 targets
#define TPB  32                // targets per bucket
#define CAPT 128               // per-target slots: mean 64, global max ~100
#define OVF_CAP 64             // overflow records (expected ~0)

// weight = clip(att,0,1) * 0.9^delay, delay in [0,6). Exact bit-product.
__device__ __forceinline__ float edge_weight(float a, int d) {
  float w = fminf(fmaxf(a, 0.0f), 1.0f);
  float r = (d & 1) ? 0.9f : 1.0f;
  r = (d & 2) ? r * 0.81f   : r;
  r = (d & 4) ? r * 0.6561f : r;
  return w * r;
}

// ---------------------------------------------------------------------------
// K1: transpose 64 sources of spikes + LDS counting-sort of 4096 edges by
// bucket + ONE contiguous 32 KB flush (full lines, no padding, no spill).
// rec[g][i], i in [0,4096): records {meta = tl<<14 | src, w_bits} grouped by
// bucket; ofse[g][bkt] = end<<16 | start (within-block slice bounds).
__global__ __launch_bounds__(1024) void produce(
    const float* __restrict__ spikes,
    const float* __restrict__ att,
    const int*   __restrict__ tgt,
    const int*   __restrict__ del,
    float*        __restrict__ spikesT,
    int2*         __restrict__ rec,
    unsigned int* __restrict__ ofse) {
  __shared__ float tile[64][33];        // 8.4 KB
  __shared__ int4  sbuf4[EPG / 2];      // 32 KB: 4096 int2 records
  __shared__ int   cnt5[NBKT], cur5[NBKT], sofs5[NBKT];
  __shared__ int   wtot[8];
  int2* buf = (int2*)sbuf4;

  const int g   = blockIdx.x;
  const int tid = threadIdx.x;
  if (tid < NBKT) cnt5[tid] = 0;

  // -- transpose sources [g*64, g*64+64): load half
  const int s0 = g * 64;
  {
    const int x = tid & 63, y = tid >> 6;       // y 0..15
    tile[x][y]      = spikes[(size_t)y        * S_ + s0 + x];
    tile[x][y + 16] = spikes[(size_t)(y + 16) * S_ + s0 + x];
  }

  // -- load my 4 edges (kept in registers across all phases)
  const int e4  = g * 1024 + tid;
  int4   t = reinterpret_cast<const int4*>(tgt)[e4];
  float4 a = reinterpret_cast<const float4*>(att)[e4];
  int4   d = reinterpret_cast<const int4*>(del)[e4];
  const int src = (e4 * 4) >> 6;                // 4 consecutive edges: 1 source

  __syncthreads();                              // cnt5 init + tile visible

  // -- transpose write
  {
    const int b = tid & 31, j = tid >> 5;       // j 0..31
    spikesT[(size_t)(s0 + j)      * 32 + b] = tile[j][b];
    spikesT[(size_t)(s0 + j + 32) * 32 + b] = tile[j + 32][b];
  }

  // -- pass 1: bucket histogram (ds_add, no return needed)
  const int bk0 = t.x >> 5, bk1 = t.y >> 5, bk2 = t.z >> 5, bk3 = t.w >> 5;
  __hip_atomic_fetch_add(&cnt5[bk0], 1, __ATOMIC_RELAXED, __HIP_MEMORY_SCOPE_WORKGROUP);
  __hip_atomic_fetch_add(&cnt5[bk1], 1, __ATOMIC_RELAXED, __HIP_MEMORY_SCOPE_WORKGROUP);
  __hip_atomic_fetch_add(&cnt5[bk2], 1, __ATOMIC_RELAXED, __HIP_MEMORY_SCOPE_WORKGROUP);
  __hip_atomic_fetch_add(&cnt5[bk3], 1, __ATOMIC_RELAXED, __HIP_MEMORY_SCOPE_WORKGROUP);
  __syncthreads();

  // -- exclusive scan of 512 bins: waves 0..7 shuffle-scan 64 each + combine
  int v = 0, incl = 0;
  if (tid < NBKT) {
    v = cnt5[tid];
    incl = v;
#pragma unroll
    for (int off = 1; off < 64; off <<= 1) {
      int u = __shfl_up(incl, off);
      if ((tid & 63) >= off) incl += u;
    }
    if ((tid & 63) == 63) wtot[tid >> 6] = incl;
  }
  __syncthreads();
  if (tid < NBKT) {
    int base = 0;
    const int wv = tid >> 6;
    for (int i = 0; i < wv; ++i) base += wtot[i];
    const int start = base + incl - v;
    sofs5[tid] = start;
    cur5[tid]  = start;
  }
  __syncthreads();

  // -- pass 2: weight + place into LDS at bucket cursor (exact, no overflow)
#define PUT(BK, TL, AV, DV)                                                   \
  {                                                                           \
    int p = __hip_atomic_fetch_add(&cur5[BK], 1, __ATOMIC_RELAXED,            \
                                   __HIP_MEMORY_SCOPE_WORKGROUP);             \
    buf[p] = make_int2(((TL) << 14) | src,                                    \
                       __float_as_int(edge_weight((AV), (DV))));              \
  }
  PUT(bk0, t.x & 31, a.x, d.x)
  PUT(bk1, t.y & 31, a.y, d.y)
  PUT(bk2, t.z & 31, a.z, d.z)
  PUT(bk3, t.w & 31, a.w, d.w)
#undef PUT
  __syncthreads();

  // -- flush: one contiguous 32 KB stream of full lines (int4 x2 per thread)
  int4* recO = reinterpret_cast<int4*>(rec) + (size_t)g * (EPG / 2);
  recO[tid]        = sbuf4[tid];
  recO[tid + 1024] = sbuf4[tid + 1024];
  if (tid < NBKT)
    ofse[(size_t)g * NBKT + tid] =
        ((unsigned)cur5[tid] << 16) | (unsigned)sofs5[tid];   // coalesced
}

// ---------------------------------------------------------------------------
// K2 (v6): NO fine sort. Per-target count ~ Poisson(64), global max ~100, so
// each target gets a FIXED 128-slot LDS slice; pass 1 places records directly
// at srt[tl*CAPT + cur32[tl]++]. Deletes: raw buffer (20KB), scan256/sstart,
// h32 histogram, scan32, the whole rank+scatter pass. Tiny LDS overflow list
// (drained in gather) keeps it correct if a slice ever exceeds 128.
// LDS 51.4KB -> ~38.7KB => 4 blocks/CU (32 waves, occupancy cap), 2x the
// latency hiding for pass-1 global reads + gather chain.
__global__ __launch_bounds__(512) void consume(
    const int2*  __restrict__ rec,
    const unsigned int* __restrict__ ofse,
    const float* __restrict__ spikesT,
    float* __restrict__ out) {
  __shared__ int2  srt[TPB * CAPT];     // 32 KB, target t owns [t*CAPT, ...)
  __shared__ float otile[TPB][33];      // 4.2 KB
  __shared__ unsigned sse[GP_];         // 1 KB
  __shared__ int   cur32[TPB];
  __shared__ int2  ovf[OVF_CAP];
  __shared__ int   ovfn;

  const int k   = blockIdx.x;
  const int tid = threadIdx.x;
  const int b   = tid & 31;
  const int hw  = tid >> 5;             // 0..15

  if (tid < TPB) cur32[tid] = tid * CAPT;
  if (tid == 0)  ovfn = 0;
  if (tid < GP_) sse[tid] = ofse[(size_t)tid * NBKT + k];   // strided, 1 instr
  __syncthreads();

  // pass 1: 8 lanes per slice, 64 slices concurrent; direct placement.
  {
    const int grp = tid >> 3;           // 0..63
    const int l8  = tid & 7;
    for (int it = 0; it < 4; ++it) {
      const int g = grp + it * 64;
      const unsigned u = sse[g];
      const int st = (int)(u & 0xFFFF);
      const int n  = (int)(u >> 16) - st;
      const int2* slice = rec + (size_t)g * EPG + st;
      for (int j = l8; j < n; j += 8) {
        int2 r = slice[j];
        const int tl = (r.x >> 14) & 31;
        int p = __hip_atomic_fetch_add(&cur32[tl], 1, __ATOMIC_RELAXED,
                                       __HIP_MEMORY_SCOPE_WORKGROUP);
        if (p < (tl + 1) * CAPT) {
          srt[p] = r;
        } else {
          int q = __hip_atomic_fetch_add(&ovfn, 1, __ATOMIC_RELAXED,
                                         __HIP_MEMORY_SCOPE_WORKGROUP);
          if (q < OVF_CAP) ovf[q] = r;
        }
      }
    }
  }
  __syncthreads();

  // gather: half-wave hw owns targets hw (acc0) and hw+16 (acc1); lane=batch.
  // Interleaved 4+4 so 8 srt reads + 8 spikesT loads are outstanding.
  float acc0 = 0.f, acc1 = 0.f;
  int e0 = hw * CAPT;
  int e1 = (hw + 16) * CAPT;
  const int e0e = min(cur32[hw],      (hw + 1)  * CAPT);
  const int e1e = min(cur32[hw + 16], (hw + 17) * CAPT);

  for (; e0 + 4 <= e0e && e1 + 4 <= e1e; e0 += 4, e1 += 4) {
    int2 r0 = srt[e0], r1 = srt[e0 + 1], r2 = srt[e0 + 2], r3 = srt[e0 + 3];
    int2 q0 = srt[e1], q1 = srt[e1 + 1], q2 = srt[e1 + 2], q3 = srt[e1 + 3];
    float s0 = spikesT[(size_t)(r0.x & 0x3FFF) * 32 + b];
    float s1 = spikesT[(size_t)(r1.x & 0x3FFF) * 32 + b];
    float s2 = spikesT[(size_t)(r2.x & 0x3FFF) * 32 + b];
    float s3 = spikesT[(size_t)(r3.x & 0x3FFF) * 32 + b];
    float u0 = spikesT[(size_t)(q0.x & 0x3FFF) * 32 + b];
    float u1 = spikesT[(size_t)(q1.x & 0x3FFF) * 32 + b];
    float u2 = spikesT[(size_t)(q2.x & 0x3FFF) * 32 + b];
    float u3 = spikesT[(size_t)(q3.x & 0x3FFF) * 32 + b];
    acc0 = fmaf(__int_as_float(r0.y), s0, acc0);
    acc0 = fmaf(__int_as_float(r1.y), s1, acc0);
    acc0 = fmaf(__int_as_float(r2.y), s2, acc0);
    acc0 = fmaf(__int_as_float(r3.y), s3, acc0);
    acc1 = fmaf(__int_as_float(q0.y), u0, acc1);
    acc1 = fmaf(__int_as_float(q1.y), u1, acc1);
    acc1 = fmaf(__int_as_float(q2.y), u2, acc1);
    acc1 = fmaf(__int_as_float(q3.y), u3, acc1);
  }
  // drain target A
  for (; e0 + 4 <= e0e; e0 += 4) {
    int2 r0 = srt[e0], r1 = srt[e0 + 1], r2 = srt[e0 + 2], r3 = srt[e0 + 3];
    float s0 = spikesT[(size_t)(r0.x & 0x3FFF) * 32 + b];
    float s1 = spikesT[(size_t)(r1.x & 0x3FFF) * 32 + b];
    float s2 = spikesT[(size_t)(r2.x & 0x3FFF) * 32 + b];
    float s3 = spikesT[(size_t)(r3.x & 0x3FFF) * 32 + b];
    acc0 = fmaf(__int_as_float(r0.y), s0, acc0);
    acc0 = fmaf(__int_as_float(r1.y), s1, acc0);
    acc0 = fmaf(__int_as_float(r2.y), s2, acc0);
    acc0 = fmaf(__int_as_float(r3.y), s3, acc0);
  }
  for (; e0 < e0e; ++e0) {
    int2 r = srt[e0];
    acc0 = fmaf(__int_as_float(r.y), spikesT[(size_t)(r.x & 0x3FFF) * 32 + b], acc0);
  }
  // drain target B
  for (; e1 + 4 <= e1e; e1 += 4) {
    int2 q0 = srt[e1], q1 = srt[e1 + 1], q2 = srt[e1 + 2], q3 = srt[e1 + 3];
    float u0 = spikesT[(size_t)(q0.x & 0x3FFF) * 32 + b];
    float u1 = spikesT[(size_t)(q1.x & 0x3FFF) * 32 + b];
    float u2 = spikesT[(size_t)(q2.x & 0x3FFF) * 32 + b];
    float u3 = spikesT[(size_t)(q3.x & 0x3FFF) * 32 + b];
    acc1 = fmaf(__int_as_float(q0.y), u0, acc1);
    acc1 = fmaf(__int_as_float(q1.y), u1, acc1);
    acc1 = fmaf(__int_as_float(q2.y), u2, acc1);
    acc1 = fmaf(__int_as_float(q3.y), u3, acc1);
  }
  for (; e1 < e1e; ++e1) {
    int2 q = srt[e1];
    acc1 = fmaf(__int_as_float(q.y), spikesT[(size_t)(q.x & 0x3FFF) * 32 + b], acc1);
  }

  // overflow drain (expected empty; correctness net for slice > CAPT)
  const int no = min(ovfn, OVF_CAP);
  for (int j = 0; j < no; ++j) {
    int2 r = ovf[j];
    const int tl = (r.x >> 14) & 31;
    float s = spikesT[(size_t)(r.x & 0x3FFF) * 32 + b];
    float w = __int_as_float(r.y);
    if (tl == hw)      acc0 = fmaf(w, s, acc0);
    if (tl == hw + 16) acc1 = fmaf(w, s, acc1);
  }

  // transpose 32x32 tile and write out coalesced
  otile[hw][b]      = acc0;
  otile[hw + 16][b] = acc1;
  __syncthreads();
  const int bb = tid >> 4;              // batch 0..31
  const int cc = (tid & 15) * 2;        // target pair
  float2 o2 = make_float2(otile[cc][bb], otile[cc + 1][bb]);
  *reinterpret_cast<float2*>(&out[(size_t)bb * T_ + k * 32 + cc]) = o2;
}

// ---------------------------------------------------------------------------
__global__ void zero_floats(float* __restrict__ p, int n) {
  int i = blockIdx.x * blockDim.x + threadIdx.x;
  if (i < n) p[i] = 0.0f;
}

// Emergency fallback (tiny ws): direct global atomics, weights inline.
__global__ void naive_kernel(const float* __restrict__ spikes,
                             const float* __restrict__ att,
                             const int*   __restrict__ tgt,
                             const int*   __restrict__ del,
                             float*       __restrict__ out) {
  int i = blockIdx.x * blockDim.x + threadIdx.x;
  if (i >= NEDGES) return;
  int   s = i >> 6;
  int   t = tgt[i];
  float w = edge_weight(att[i], del[i]);
  for (int b = 0; b < B_; ++b)
    unsafeAtomicAdd(&out[(size_t)b * T_ + t], w * spikes[(size_t)b * S_ + s]);
}

// ---------------------------------------------------------------------------
extern "C" void kernel_launch(void* const* d_in, const int* in_sizes, int n_in,
                              void* d_out, int out_size, void* d_ws, size_t ws_size,
                              hipStream_t stream) {
  const float* spikes = (const float*)d_in[0];
  const float* att    = (const float*)d_in[1];
  const int*   tgt    = (const int*)d_in[2];
  const int*   del    = (const int*)d_in[3];
  float*       out    = (float*)d_out;

  const size_t spikesT_bytes = (size_t)S_ * B_ * sizeof(float);         // 2 MB
  const size_t rec_bytes     = (size_t)NEDGES * sizeof(int2);           // 8 MB
  const size_t ofse_bytes    = (size_t)GP_ * NBKT * sizeof(unsigned);   // 512 KB
  const size_t need = spikesT_bytes + rec_bytes + ofse_bytes + 64;

  if (ws_size < need) {
    zero_floats<<<(B_ * T_ + 255) / 256, 256, 0, stream>>>(out, B_ * T_);
    naive_kernel<<<(NEDGES + 255) / 256, 256, 0, stream>>>(spikes, att, tgt, del, out);
    return;
  }

  char* p = (char*)d_ws;
  float*        spikesT = (float*)p;        p += spikesT_bytes;
  int2*         rec     = (int2*)p;         p += rec_bytes;
  unsigned int* ofse    = (unsigned int*)p;

  produce<<<GP_, 1024, 0, stream>>>(spikes, att, tgt, del, spikesT, rec, ofse);
  consume<<<NBKT, 512, 0, stream>>>(rec, ofse, spikesT, out);
}